// Round 10
// baseline (729.167 us; speedup 1.0000x reference)
//
#include <hip/hip_runtime.h>

// ---------------------------------------------------------------------------
// VQ-VAE forward (NCHW). Round 10: M-group split (MGS) for grid-limited MFMA
//  kernels. R9 post-mortem: conv4 occupancy 20% — NP=2 halved grid to 512
//  blocks = 2 blocks/CU (grid-limited, not VGPR-limited). conv3/deconv1 same.
//  Fix: each block computes half the cout tiles (MGS=2) -> 1024 blocks =
//  4 blocks/CU, acc regs halve. Per-accumulator op order unchanged ->
//  absmax must stay exactly 2.44e-4. conv2/deconv2/conv1/vq/dec3 unchanged.
// ---------------------------------------------------------------------------

using short8  = __attribute__((ext_vector_type(8))) short;
using short4v = __attribute__((ext_vector_type(4))) short;
using floatx4 = __attribute__((ext_vector_type(4))) float;

__device__ inline unsigned short bf16rn(float f) {
  unsigned u = __float_as_uint(f);
  unsigned r = (u + 0x7fffu + ((u >> 16) & 1u)) >> 16;
  return (unsigned short)r;
}
__device__ inline float bf2f1(short h) {
  return __uint_as_float(((unsigned)(unsigned short)h) << 16);
}

// ---- deconv tap tables: entry e -> (ky,kx) weight tap
__device__ const int DKY[9]  = {1, 1, 1, 2, 0, 2, 2, 0, 0};
__device__ const int DKX[9]  = {1, 2, 0, 1, 1, 2, 0, 2, 0};

// ---------------- ring zero (split pair) ----------------------------------
__global__ __launch_bounds__(256) void ring_zero(short* __restrict__ h,
                                                 short* __restrict__ l,
                                                 int nimg, int PH, int PW, int C) {
  const int RC = (2 * PW + 2 * (PH - 2)) * C;
  int t = blockIdx.x * 256 + threadIdx.x;
  if (t >= nimg * RC) return;
  const int nl = t / RC;
  int rem = t - nl * RC;
  const int p = rem / C;
  const int ch = rem - p * C;
  int r, c;
  if (p < 2 * PW) {
    r = (p < PW) ? 0 : PH - 1;
    c = (p < PW) ? p : p - PW;
  } else {
    int q = p - 2 * PW;
    if (q < PH - 2) { r = 1 + q; c = 0; }
    else { r = 1 + q - (PH - 2); c = PW - 1; }
  }
  const size_t a = (((size_t)nl * PH + r) * PW + c) * C + ch;
  h[a] = 0; l[a] = 0;
}

// ---------------- ring zero (single buffer) -------------------------------
__global__ __launch_bounds__(256) void ring_zero1(short* __restrict__ h,
                                                  int nimg, int PH, int PW, int C) {
  const int RC = (2 * PW + 2 * (PH - 2)) * C;
  int t = blockIdx.x * 256 + threadIdx.x;
  if (t >= nimg * RC) return;
  const int nl = t / RC;
  int rem = t - nl * RC;
  const int p = rem / C;
  const int ch = rem - p * C;
  int r, c;
  if (p < 2 * PW) {
    r = (p < PW) ? 0 : PH - 1;
    c = (p < PW) ? p : p - PW;
  } else {
    int q = p - 2 * PW;
    if (q < PH - 2) { r = 1 + q; c = 0; }
    else { r = 1 + q - (PH - 2); c = PW - 1; }
  }
  h[(((size_t)nl * PH + r) * PW + c) * C + ch] = 0;
}

// ---------------- conv1: fp32 direct, writes xt [nh][130][130][32] --------
__global__ __launch_bounds__(256) void conv1_xt(const float* __restrict__ x,
                                                const float* __restrict__ w,
                                                const float* __restrict__ bias,
                                                short* __restrict__ oh,
                                                short* __restrict__ ol, int NH) {
  int t = blockIdx.x * 256 + threadIdx.x;
  if (t >= NH * 128 * 128) return;
  const int px = t & 16383;
  const int n  = t >> 14;
  const int r = px >> 7, c = px & 127;
  const int ih0 = 2 * r - 1, iw0 = 2 * c - 1;
  float acc[32];
#pragma unroll
  for (int o = 0; o < 32; ++o) acc[o] = bias[o];
  const float* ip = x + (size_t)n * 2 * 65536;
#pragma unroll
  for (int ic = 0; ic < 2; ++ic, ip += 65536) {
    float v[9];
#pragma unroll
    for (int kh = 0; kh < 3; ++kh) {
      const int ih = ih0 + kh;
#pragma unroll
      for (int kw = 0; kw < 3; ++kw) {
        const int iw = iw0 + kw;
        const bool ok = (ih >= 0) && (ih < 256) && (iw >= 0) && (iw < 256);
        v[kh * 3 + kw] = ok ? ip[ih * 256 + iw] : 0.f;
      }
    }
#pragma unroll
    for (int o = 0; o < 32; ++o) {
      float s = acc[o];
#pragma unroll
      for (int k = 0; k < 9; ++k) s = fmaf(v[k], w[(o * 2 + ic) * 9 + k], s);
      acc[o] = s;
    }
  }
  const size_t base = (((size_t)n * 130 + r + 1) * 130 + (c + 1)) * 32;
  short8 vh[4], vl[4];
#pragma unroll
  for (int g = 0; g < 4; ++g) {
#pragma unroll
    for (int kk = 0; kk < 8; ++kk) {
      const float rv = fmaxf(acc[g * 8 + kk], 0.f);
      const unsigned short hh = bf16rn(rv);
      vh[g][kk] = (short)hh;
      vl[g][kk] = (short)bf16rn(rv - __uint_as_float((unsigned)hh << 16));
    }
    *(short8*)(oh + base + g * 8) = vh[g];
    *(short8*)(ol + base + g * 8) = vl[g];
  }
}

// ---------------- A-frag prep: conv weights [COUT][CIN][3][3], split ------
template<int CIN, int COUT>
__global__ __launch_bounds__(256) void wprep_conv(const float* __restrict__ w,
                                                  short* __restrict__ hi,
                                                  short* __restrict__ lo) {
  constexpr int MT = COUT / 16;
  const int t = blockIdx.x * 256 + threadIdx.x;
  const int j = t & 7;
  const int lane = (t >> 3) & 63;
  const int g = t >> 9;
  const int mt = g % MT;
  const int s = g / MT;
  const int icb = s / 9, tap = s - icb * 9;
  const int kh = tap / 3, kw = tap - kh * 3;
  const int m = mt * 16 + (lane & 15);
  const int ic = icb * 32 + ((lane >> 4) << 3) + j;
  const float v = w[((m * CIN + ic) * 3 + kh) * 3 + kw];
  const unsigned short h = bf16rn(v);
  hi[t] = (short)h;
  lo[t] = (short)bf16rn(v - __uint_as_float((unsigned)h << 16));
}

// ---------------- deconv A-frag prep: [CIN][COUT][3][3], hi-only ----------
template<int CIN, int COUT>
__global__ __launch_bounds__(256) void wprep_dec_h(const float* __restrict__ w,
                                                   short* __restrict__ hi) {
  constexpr int MT = COUT / 16, ICB = CIN / 32;
  const int t = blockIdx.x * 256 + threadIdx.x;
  const int j = t & 7;
  const int lane = (t >> 3) & 63;
  const int g = t >> 9;
  const int mt = g % MT;
  const int u = g / MT;
  const int icb = u % ICB;
  const int e = u / ICB;
  const int ky = DKY[e], kx = DKX[e];
  const int m = mt * 16 + (lane & 15);
  const int ic = icb * 32 + ((lane >> 4) << 3) + j;
  hi[t] = (short)bf16rn(w[((ic * COUT + m) * 3 + ky) * 3 + kx]);
}

// -- generic strided conv MFMA (split xt -> split xt), NP tiles, MGS groups -
template<int CIN, int COUT, int OH, int OW, int S, int PHI, int PWI, int PHO, int PWO, int NP, int MGS>
__global__ __launch_bounds__(256) void conv_mfma_xt(
    const short* __restrict__ xih, const short* __restrict__ xil,
    const short* __restrict__ ah,  const short* __restrict__ al,
    const float* __restrict__ bias,
    short* __restrict__ xoh, short* __restrict__ xol) {
  constexpr int MTF = COUT / 16, MTB = MTF / MGS, ICB = CIN / 32;
  constexpr int PXB = 64 * NP, TPB = OH * OW / PXB;
  const int b = blockIdx.x;
  const int mg = b % MGS;
  const int bb = b / MGS;
  const int n = bb / TPB, pt = bb % TPB;
  const int mt0 = mg * MTB;
  const int lane = threadIdx.x & 63, wave = threadIdx.x >> 6;
  const int quad = lane >> 4;
  int rr[NP], cc[NP];
  size_t bbase[NP];
#pragma unroll
  for (int p = 0; p < NP; ++p) {
    const int pl = pt * PXB + wave * (16 * NP) + p * 16 + (lane & 15);
    rr[p] = pl / OW; cc[p] = pl % OW;
    bbase[p] = (((size_t)n * PHI + S * rr[p]) * PWI + S * cc[p]) * CIN + quad * 8;
  }

  floatx4 acc[MTB][NP];
#pragma unroll
  for (int mt = 0; mt < MTB; ++mt)
#pragma unroll
    for (int p = 0; p < NP; ++p) acc[mt][p] = (floatx4){0.f, 0.f, 0.f, 0.f};

  const short8* __restrict__ ah8 = (const short8*)ah;
  const short8* __restrict__ al8 = (const short8*)al;

  for (int icb = 0; icb < ICB; ++icb) {
#pragma unroll
    for (int tap = 0; tap < 9; ++tap) {
      const int kh = tap / 3, kw = tap - kh * 3;
      short8 bh[NP], bl[NP];
#pragma unroll
      for (int p = 0; p < NP; ++p) {
        const size_t be = bbase[p] + (size_t)(kh * PWI + kw) * CIN + icb * 32;
        bh[p] = *(const short8*)(xih + be);
        bl[p] = *(const short8*)(xil + be);
      }
#pragma unroll
      for (int mt = 0; mt < MTB; ++mt) {
        const int fi = ((icb * 9 + tap) * MTF + (mt0 + mt)) * 64 + lane;
        const short8 wh = ah8[fi];
        const short8 wl = al8[fi];
#pragma unroll
        for (int p = 0; p < NP; ++p) {
          acc[mt][p] = __builtin_amdgcn_mfma_f32_16x16x32_bf16(wh, bh[p], acc[mt][p], 0, 0, 0);
          acc[mt][p] = __builtin_amdgcn_mfma_f32_16x16x32_bf16(wh, bl[p], acc[mt][p], 0, 0, 0);
          acc[mt][p] = __builtin_amdgcn_mfma_f32_16x16x32_bf16(wl, bh[p], acc[mt][p], 0, 0, 0);
        }
      }
    }
  }
#pragma unroll
  for (int p = 0; p < NP; ++p) {
    const size_t ob = (((size_t)n * PHO + rr[p] + 1) * PWO + (cc[p] + 1)) * COUT + quad * 4;
#pragma unroll
    for (int mt = 0; mt < MTB; ++mt) {
      short4v sh, sl;
#pragma unroll
      for (int q = 0; q < 4; ++q) {
        const float v = fmaxf(acc[mt][p][q] + bias[(mt0 + mt) * 16 + quad * 4 + q], 0.f);
        const unsigned short hh = bf16rn(v);
        sh[q] = (short)hh;
        sl[q] = (short)bf16rn(v - __uint_as_float((unsigned)hh << 16));
      }
      *(short4v*)(xoh + ob + (mt0 + mt) * 16) = sh;
      *(short4v*)(xol + ob + (mt0 + mt) * 16) = sl;
    }
  }
}

// -- fused transposed conv, plain bf16, NP pixel-tiles, MGS m-groups -------
template<int CIN, int COUT, int IH, int IW, int PHI, int PWI, int PHO, int PWO, int NP, int MGS>
__global__ __launch_bounds__(256) void deconv_bf16_xt(
    const short* __restrict__ xih, const short* __restrict__ ah,
    const float* __restrict__ bias, short* __restrict__ xoh) {
  constexpr int MTF = COUT / 16, MTB = MTF / MGS, ICB = CIN / 32;
  constexpr int PXB = 64 * NP, TPB = IH * IW / PXB;
  constexpr int PHE[9] = {0, 1, 1, 2, 2, 3, 3, 3, 3};
  constexpr int DE[9]  = {0, 0, 1, 0, 2, 0, 1, 2, 3};
  const int b = blockIdx.x;
  const int mg = b % MGS;
  const int bb = b / MGS;
  const int n = bb / TPB, pt = bb % TPB;
  const int mt0 = mg * MTB;
  const int lane = threadIdx.x & 63, wave = threadIdx.x >> 6;
  const int quad = lane >> 4;
  int ii[NP], jj[NP];
  size_t p00[NP];
#pragma unroll
  for (int p = 0; p < NP; ++p) {
    const int pl = pt * PXB + wave * (16 * NP) + p * 16 + (lane & 15);
    ii[p] = pl / IW; jj[p] = pl % IW;
    p00[p] = (((size_t)n * PHI + (ii[p] + 1)) * PWI + (jj[p] + 1)) * CIN + quad * 8;
  }

  floatx4 acc[4][MTB][NP];
#pragma unroll
  for (int ph = 0; ph < 4; ++ph)
#pragma unroll
    for (int mt = 0; mt < MTB; ++mt)
#pragma unroll
      for (int p = 0; p < NP; ++p) acc[ph][mt][p] = (floatx4){0.f, 0.f, 0.f, 0.f};

  const short8* __restrict__ ah8 = (const short8*)ah;
  for (int icb = 0; icb < ICB; ++icb) {
    short8 bh[NP][4];
#pragma unroll
    for (int p = 0; p < NP; ++p)
#pragma unroll
      for (int d = 0; d < 4; ++d)
        bh[p][d] = *(const short8*)(xih + p00[p] +
                                    (size_t)((d >> 1) * PWI + (d & 1)) * CIN + icb * 32);
#pragma unroll
    for (int e = 0; e < 9; ++e) {
      const int ph = PHE[e], d = DE[e];
#pragma unroll
      for (int mt = 0; mt < MTB; ++mt) {
        const short8 wh = ah8[((e * ICB + icb) * MTF + (mt0 + mt)) * 64 + lane];
#pragma unroll
        for (int p = 0; p < NP; ++p)
          acc[ph][mt][p] = __builtin_amdgcn_mfma_f32_16x16x32_bf16(
              wh, bh[p][d], acc[ph][mt][p], 0, 0, 0);
      }
    }
  }
#pragma unroll
  for (int p = 0; p < NP; ++p)
#pragma unroll
    for (int ph = 0; ph < 4; ++ph) {
      const int oy = 2 * ii[p] + (ph >> 1), ox = 2 * jj[p] + (ph & 1);
      const size_t ob = (((size_t)n * PHO + oy + 1) * PWO + (ox + 1)) * COUT + quad * 4;
#pragma unroll
      for (int mt = 0; mt < MTB; ++mt) {
        short4v sh;
#pragma unroll
        for (int q = 0; q < 4; ++q)
          sh[q] = (short)bf16rn(fmaxf(acc[ph][mt][p][q] + bias[(mt0 + mt) * 16 + quad * 4 + q], 0.f));
        *(short4v*)(xoh + ob + (mt0 + mt) * 16) = sh;
      }
    }
}

// ---------------- conv4 MFMA, NP=2, 2 m-groups ----------------------------
__global__ __launch_bounds__(256) void conv4_mfma(
    const short* __restrict__ xthi, const short* __restrict__ xtlo,
    const short* __restrict__ ahi,  const short* __restrict__ alo,
    const float* __restrict__ bias,
    short* __restrict__ ench, short* __restrict__ encl) {
  const int b    = blockIdx.x;         // N*16 blocks: (n, pt 0..7, mg 0..1)
  const int n    = b >> 4;
  const int mg   = b & 1;
  const int pt   = (b >> 1) & 7;
  const int mt0  = mg * 4;
  const int lane = threadIdx.x & 63;
  const int wave = threadIdx.x >> 6;
  const int kq   = lane >> 4;
  int pl[2];
  size_t bbase[2];
#pragma unroll
  for (int p = 0; p < 2; ++p) {
    pl[p] = pt * 128 + wave * 32 + p * 16 + (lane & 15);
    const int r = pl[p] >> 5, c = pl[p] & 31;
    bbase[p] = (((size_t)n * 34 + r) * 34 + c) * 128 + kq * 8;
  }

  floatx4 acc[4][2];
#pragma unroll
  for (int mt = 0; mt < 4; ++mt)
#pragma unroll
    for (int p = 0; p < 2; ++p) acc[mt][p] = (floatx4){0.f, 0.f, 0.f, 0.f};

  const short8* __restrict__ ah8 = (const short8*)ahi;
  const short8* __restrict__ al8 = (const short8*)alo;

  int s = 0;
  for (int icb = 0; icb < 4; ++icb) {
#pragma unroll
    for (int tap = 0; tap < 9; ++tap, ++s) {
      const int kh = tap / 3, kw = tap - kh * 3;
      short8 bh[2], bl[2];
#pragma unroll
      for (int p = 0; p < 2; ++p) {
        const size_t be = bbase[p] + (size_t)(kh * 34 + kw) * 128 + icb * 32;
        bh[p] = *(const short8*)(xthi + be);
        bl[p] = *(const short8*)(xtlo + be);
      }
#pragma unroll
      for (int mt = 0; mt < 4; ++mt) {
        const int fi = ((s * 8 + (mt0 + mt)) << 6) + lane;
        const short8 ah = ah8[fi];
        const short8 al = al8[fi];
#pragma unroll
        for (int p = 0; p < 2; ++p) {
          acc[mt][p] = __builtin_amdgcn_mfma_f32_16x16x32_bf16(ah, bh[p], acc[mt][p], 0, 0, 0);
          acc[mt][p] = __builtin_amdgcn_mfma_f32_16x16x32_bf16(ah, bl[p], acc[mt][p], 0, 0, 0);
          acc[mt][p] = __builtin_amdgcn_mfma_f32_16x16x32_bf16(al, bh[p], acc[mt][p], 0, 0, 0);
        }
      }
    }
  }
#pragma unroll
  for (int p = 0; p < 2; ++p) {
    const size_t obase = (size_t)n * 128 * 1024 + pl[p];
#pragma unroll
    for (int mt = 0; mt < 4; ++mt) {
#pragma unroll
      for (int q = 0; q < 4; ++q) {
        const int cout = (mt0 + mt) * 16 + kq * 4 + q;
        const float rr = fmaxf(acc[mt][p][q] + bias[cout], 0.f);
        const unsigned short h = bf16rn(rr);
        const size_t oi = obase + (size_t)cout * 1024;
        ench[oi] = (short)h;
        encl[oi] = (short)bf16rn(rr - __uint_as_float((unsigned)h << 16));
      }
    }
  }
}

// ------------------------------- VQ ---------------------------------------
__global__ __launch_bounds__(256) void vq_norms(const float* __restrict__ emb,
                                                float* __restrict__ norms) {
  int jj = blockIdx.x * 256 + threadIdx.x;
  if (jj < 512) {
    float s = 0.f;
    const float* e = emb + jj * 64;
#pragma unroll
    for (int k = 0; k < 64; ++k) s = fmaf(e[k], e[k], s);
    norms[jj] = s;
  }
}

__global__ __launch_bounds__(256) void emb_prep(const float* __restrict__ emb,
                                                short* __restrict__ hi,
                                                short* __restrict__ lo) {
  const int t = blockIdx.x * 256 + threadIdx.x;  // < 32768
  const int j  = t & 7;
  const int l  = (t >> 3) & 63;
  const int kk = (t >> 9) & 1;
  const int ct = t >> 10;
  const int code = ct * 16 + (l & 15);
  const int k = kk * 32 + ((l >> 4) << 3) + j;
  const float v = emb[code * 64 + k];
  const unsigned short h = bf16rn(v);
  hi[t] = (short)h;
  lo[t] = (short)bf16rn(v - __uint_as_float((unsigned)h << 16));
}

// scoring split-bf16 (proven); gather writes single-bf16 xt for decoder.
__global__ __launch_bounds__(256) void vq_mfma(
    const short* __restrict__ fhi, const short* __restrict__ flo,
    const short* __restrict__ ebh, const short* __restrict__ ebl,
    const float* __restrict__ nrm, const float* __restrict__ emb,
    short* __restrict__ d1h) {
  __shared__ int sidx[64];
  const int lane = threadIdx.x & 63;
  const int wave = threadIdx.x >> 6;
  const int r0 = blockIdx.x * 64 + wave * 16;
  const size_t abase = ((size_t)(r0 + (lane & 15))) * 64 + ((lane >> 4) << 3);
  short8 ah0 = *(const short8*)(fhi + abase);
  short8 ah1 = *(const short8*)(fhi + abase + 32);
  short8 al0 = *(const short8*)(flo + abase);
  short8 al1 = *(const short8*)(flo + abase + 32);

  float bestv[4] = {3.4e38f, 3.4e38f, 3.4e38f, 3.4e38f};
  int   besti[4] = {0, 0, 0, 0};
  const short8* __restrict__ ebh8 = (const short8*)ebh;
  const short8* __restrict__ ebl8 = (const short8*)ebl;
  for (int ct = 0; ct < 32; ++ct) {
    const int f0 = (ct * 2) * 64 + lane;
    const short8 b0h = ebh8[f0];
    const short8 b1h = ebh8[f0 + 64];
    const short8 b0l = ebl8[f0];
    const short8 b1l = ebl8[f0 + 64];
    floatx4 acc = {0.f, 0.f, 0.f, 0.f};
    acc = __builtin_amdgcn_mfma_f32_16x16x32_bf16(ah0, b0h, acc, 0, 0, 0);
    acc = __builtin_amdgcn_mfma_f32_16x16x32_bf16(ah1, b1h, acc, 0, 0, 0);
    acc = __builtin_amdgcn_mfma_f32_16x16x32_bf16(ah0, b0l, acc, 0, 0, 0);
    acc = __builtin_amdgcn_mfma_f32_16x16x32_bf16(ah1, b1l, acc, 0, 0, 0);
    acc = __builtin_amdgcn_mfma_f32_16x16x32_bf16(al0, b0h, acc, 0, 0, 0);
    acc = __builtin_amdgcn_mfma_f32_16x16x32_bf16(al1, b1h, acc, 0, 0, 0);
    const int code = ct * 16 + (lane & 15);
    const float nn = nrm[code];
#pragma unroll
    for (int q = 0; q < 4; ++q) {
      const float sc = nn - 2.f * acc[q];
      if (sc < bestv[q]) { bestv[q] = sc; besti[q] = code; }
    }
  }
#pragma unroll
  for (int off = 1; off < 16; off <<= 1) {
#pragma unroll
    for (int q = 0; q < 4; ++q) {
      const float ov = __shfl_xor(bestv[q], off, 64);
      const int   oi = __shfl_xor(besti[q], off, 64);
      if (ov < bestv[q] || (ov == bestv[q] && oi < besti[q])) {
        bestv[q] = ov; besti[q] = oi;
      }
    }
  }
  if ((lane & 15) == 0) {
#pragma unroll
    for (int q = 0; q < 4; ++q)
      sidx[wave * 16 + (lane >> 4) * 4 + q] = besti[q];
  }
  __syncthreads();
  const int row  = threadIdx.x >> 2;
  const int part = threadIdx.x & 3;
  const int rid = blockIdx.x * 64 + row;
  const int n  = rid >> 11;
  const int ch = (rid >> 4) & 127;
  const int pb = rid & 15;
  const int gi = sidx[row];
  const float4* src = (const float4*)(emb + (size_t)gi * 64 + part * 16);
  float4 v0 = src[0], v1 = src[1], v2 = src[2], v3 = src[3];
  float vals[16] = {v0.x, v0.y, v0.z, v0.w, v1.x, v1.y, v1.z, v1.w,
                    v2.x, v2.y, v2.z, v2.w, v3.x, v3.y, v3.z, v3.w};
#pragma unroll
  for (int kk = 0; kk < 16; ++kk) {
    const int k = part * 16 + kk;
    const int pix = pb * 64 + k;
    const int r = pix >> 5, c = pix & 31;
    const size_t a = (((size_t)n * 34 + r + 1) * 34 + (c + 1)) * 128 + ch;
    d1h[a] = (short)bf16rn(vals[kk]);
  }
}

// ---------------- dec3: fp32 direct from single-bf16 xt input -------------
__global__ __launch_bounds__(256) void dec3_xt(const short* __restrict__ xh,
                                               const float* __restrict__ w,
                                               const float* __restrict__ bias,
                                               float* __restrict__ out, int NH) {
  int t = blockIdx.x * 256 + threadIdx.x;
  if (t >= NH * 128 * 128) return;
  const int px = t & 16383;
  const int nl = t >> 14;
  const int i = px >> 7, j = px & 127;
  const float b0 = bias[0];
  float a00 = b0, a01 = b0, a10 = b0, a11 = b0;
  const size_t base00 = (((size_t)nl * 130 + i + 1) * 130 + (j + 1)) * 32;
#pragma unroll
  for (int icg = 0; icg < 4; ++icg) {
    const short8 h00 = *(const short8*)(xh + base00 + icg * 8);
    const short8 h01 = *(const short8*)(xh + base00 + 32 + icg * 8);
    const short8 h10 = *(const short8*)(xh + base00 + 130 * 32 + icg * 8);
    const short8 h11 = *(const short8*)(xh + base00 + 130 * 32 + 32 + icg * 8);
#pragma unroll
    for (int kk = 0; kk < 8; ++kk) {
      const int ic = icg * 8 + kk;
      const float x00 = bf2f1(h00[kk]);
      const float x01 = bf2f1(h01[kk]);
      const float x10 = bf2f1(h10[kk]);
      const float x11 = bf2f1(h11[kk]);
      const float* wp = w + ic * 9;
      a00 = fmaf(x00, wp[4], a00);
      a01 = fmaf(x00, wp[5], fmaf(x01, wp[3], a01));
      a10 = fmaf(x00, wp[7], fmaf(x10, wp[1], a10));
      a11 = fmaf(x00, wp[8], fmaf(x01, wp[6], fmaf(x10, wp[2], fmaf(x11, wp[0], a11))));
    }
  }
  float* op = out + ((size_t)nl * 256 + 2 * i) * 256 + 2 * j;
  op[0] = a00; op[1] = a01; op[256] = a10; op[257] = a11;
}

// ---------------------------------------------------------------------------
extern "C" void kernel_launch(void* const* d_in, const int* in_sizes, int n_in,
                              void* d_out, int out_size, void* d_ws, size_t ws_size,
                              hipStream_t stream) {
  const float* x   = (const float*)d_in[0];
  const float* w1  = (const float*)d_in[1];
  const float* b1  = (const float*)d_in[2];
  const float* w2  = (const float*)d_in[3];
  const float* b2  = (const float*)d_in[4];
  const float* w3  = (const float*)d_in[5];
  const float* b3  = (const float*)d_in[6];
  const float* w4  = (const float*)d_in[7];
  const float* b4  = (const float*)d_in[8];
  const float* emb = (const float*)d_in[9];
  const float* dw1 = (const float*)d_in[10];
  const float* db1 = (const float*)d_in[11];
  const float* dw2 = (const float*)d_in[12];
  const float* db2 = (const float*)d_in[13];
  const float* dw3 = (const float*)d_in[14];
  const float* db3 = (const float*)d_in[15];
  float* outp = (float*)d_out;

  const int N = in_sizes[0] / (2 * 256 * 256);  // 64
  if (N & 1) return;
  const int NH = N / 2;

  // ---- arena (units: floats; 1 float = 2 shorts); R7-proven footprint ----
  const size_t sx3 = (size_t)N * 66 * 66 * 64;
  const size_t sx2 = (size_t)NH * 130 * 130 * 32;
  const size_t sx4 = (size_t)N * 34 * 34 * 128;
  const size_t se  = (size_t)N * 128 * 1024;
  const size_t sd1 = sx4;
  const size_t smalls = 512 + 18432 + 73728 + 147456 + 73728 + 18432 + 32768;
  const size_t need = (sx3 + sx4 + se + sd1 + smalls) * sizeof(float);
  if (ws_size < need) return;

  float* ws = (float*)d_ws;
  short* x3h = (short*)ws;                 short* x3l = x3h + sx3;   // enc split
  short* x2h = (short*)(ws + sx3);         short* x2l = x2h + sx2;
  short* x4h = (short*)(ws + sx3);         short* x4l = x4h + sx4;
  short* ech = (short*)(ws + sx3 + sx4);   short* ecl = ech + se;
  short* d1h = (short*)(ws + sx3 + sx4 + se);   // bf16-only decoder bufs
  short* d2h = (short*)ws;
  short* d3h = (short*)(ws + sx3);
  float* sm  = ws + sx3 + sx4 + se + sd1;
  float* nrm = sm;
  short* a2h = (short*)(sm + 512);                         short* a2l = a2h + 18432;
  short* a3h = (short*)(sm + 512 + 18432);                 short* a3l = a3h + 73728;
  short* a4h = (short*)(sm + 512 + 18432 + 73728);         short* a4l = a4h + 147456;
  short* ad1h = (short*)(sm + 512 + 18432 + 73728 + 147456);           // hi only
  short* ad2h = (short*)(sm + 512 + 18432 + 73728 + 147456 + 73728);   // hi only
  short* ebh = (short*)(sm + 512 + 18432 + 73728 + 147456 + 73728 + 18432); short* ebl = ebh + 32768;

  // ---- weight preps + VQ tables ----
  wprep_conv<32, 64><<<72, 256, 0, stream>>>(w2, a2h, a2l);
  wprep_conv<64, 128><<<288, 256, 0, stream>>>(w3, a3h, a3l);
  wprep_conv<128, 128><<<576, 256, 0, stream>>>(w4, a4h, a4l);
  wprep_dec_h<128, 64><<<288, 256, 0, stream>>>(dw1, ad1h);
  wprep_dec_h<64, 32><<<72, 256, 0, stream>>>(dw2, ad2h);
  vq_norms<<<2, 256, 0, stream>>>(emb, nrm);
  emb_prep<<<128, 256, 0, stream>>>(emb, ebh, ebl);

  // ---- encoder (split-bf16, NP=2; conv3 MGS=2) ----
  ring_zero<<<(int)((NH * 516 * 32 + 255) / 256), 256, 0, stream>>>(x2h, x2l, NH, 130, 130, 32);
  ring_zero<<<(int)(((size_t)N * 260 * 64 + 255) / 256), 256, 0, stream>>>(x3h, x3l, N, 66, 66, 64);
  for (int half = 0; half < 2; ++half) {
    const int n0 = half * NH;
    conv1_xt<<<NH * 16384 / 256, 256, 0, stream>>>(
        x + (size_t)n0 * 2 * 65536, w1, b1, x2h, x2l, NH);
    conv_mfma_xt<32, 64, 64, 64, 2, 130, 130, 66, 66, 2, 1>
        <<<NH * 32, 256, 0, stream>>>(x2h, x2l, a2h, a2l, b2,
                                      x3h + (size_t)n0 * 66 * 66 * 64,
                                      x3l + (size_t)n0 * 66 * 66 * 64);
  }
  ring_zero<<<(int)(((size_t)N * 132 * 128 + 255) / 256), 256, 0, stream>>>(x4h, x4l, N, 34, 34, 128);
  conv_mfma_xt<64, 128, 32, 32, 2, 66, 66, 34, 34, 2, 2>
      <<<N * 16, 256, 0, stream>>>(x3h, x3l, a3h, a3l, b3, x4h, x4l);
  conv4_mfma<<<N * 16, 256, 0, stream>>>(x4h, x4l, a4h, a4l, b4, ech, ecl);

  // ---- VQ (split scoring, bf16 gather) ----
  ring_zero1<<<(int)(((size_t)N * 132 * 128 + 255) / 256), 256, 0, stream>>>(d1h, N, 34, 34, 128);
  vq_mfma<<<N * 2048 / 64, 256, 0, stream>>>(ech, ecl, ebh, ebl, nrm, emb, d1h);

  // ---- decoder (plain bf16, NP=2; deconv1 MGS=2) ----
  ring_zero1<<<(int)(((size_t)N * 260 * 64 + 255) / 256), 256, 0, stream>>>(d2h, N, 66, 66, 64);
  deconv_bf16_xt<128, 64, 32, 32, 34, 34, 66, 66, 2, 2>
      <<<N * 16, 256, 0, stream>>>(d1h, ad1h, db1, d2h);
  ring_zero1<<<(int)((NH * 516 * 32 + 255) / 256), 256, 0, stream>>>(d3h, NH, 130, 130, 32);
  for (int half = 0; half < 2; ++half) {
    const int n0 = half * NH;
    deconv_bf16_xt<64, 32, 64, 64, 66, 66, 130, 130, 2, 1>
        <<<NH * 32, 256, 0, stream>>>(d2h + (size_t)n0 * 66 * 66 * 64,
                                      ad2h, db2, d3h);
    dec3_xt<<<NH * 16384 / 256, 256, 0, stream>>>(
        d3h, dw3, db3, outp + (size_t)n0 * 65536, NH);
  }
}

// Round 11
// 684.885 us; speedup vs baseline: 1.0647x; 1.0647x over previous
//
#include <hip/hip_runtime.h>

// ---------------------------------------------------------------------------
// VQ-VAE forward (NCHW). Round 11: conv4 LDS A-fragment staging.
//  R10 post-mortem: MGS=2 on conv4 REGRESSED (FETCH 32->109 MB, MfmaUtil
//  13%) — halving M per block doubled B-loads/MFMA and blew L2. Reverted.
//  conv3/deconv1 keep MGS=2 (small B working sets stay L2-resident, net ~-15).
//  conv4 fix: 4 waves cooperatively stage next tap's A-frags (16 KB, double-
//  buffered LDS) -> per-wave global loads/tap 20->8, A L2-traffic /4,
//  ds_read replaces L2-latency loads. Math order unchanged -> absmax 2.44e-4.
// ---------------------------------------------------------------------------

using short8  = __attribute__((ext_vector_type(8))) short;
using short4v = __attribute__((ext_vector_type(4))) short;
using floatx4 = __attribute__((ext_vector_type(4))) float;

__device__ inline unsigned short bf16rn(float f) {
  unsigned u = __float_as_uint(f);
  unsigned r = (u + 0x7fffu + ((u >> 16) & 1u)) >> 16;
  return (unsigned short)r;
}
__device__ inline float bf2f1(short h) {
  return __uint_as_float(((unsigned)(unsigned short)h) << 16);
}

// ---- deconv tap tables: entry e -> (ky,kx) weight tap
__device__ const int DKY[9]  = {1, 1, 1, 2, 0, 2, 2, 0, 0};
__device__ const int DKX[9]  = {1, 2, 0, 1, 1, 2, 0, 2, 0};

// ---------------- ring zero (split pair) ----------------------------------
__global__ __launch_bounds__(256) void ring_zero(short* __restrict__ h,
                                                 short* __restrict__ l,
                                                 int nimg, int PH, int PW, int C) {
  const int RC = (2 * PW + 2 * (PH - 2)) * C;
  int t = blockIdx.x * 256 + threadIdx.x;
  if (t >= nimg * RC) return;
  const int nl = t / RC;
  int rem = t - nl * RC;
  const int p = rem / C;
  const int ch = rem - p * C;
  int r, c;
  if (p < 2 * PW) {
    r = (p < PW) ? 0 : PH - 1;
    c = (p < PW) ? p : p - PW;
  } else {
    int q = p - 2 * PW;
    if (q < PH - 2) { r = 1 + q; c = 0; }
    else { r = 1 + q - (PH - 2); c = PW - 1; }
  }
  const size_t a = (((size_t)nl * PH + r) * PW + c) * C + ch;
  h[a] = 0; l[a] = 0;
}

// ---------------- ring zero (single buffer) -------------------------------
__global__ __launch_bounds__(256) void ring_zero1(short* __restrict__ h,
                                                  int nimg, int PH, int PW, int C) {
  const int RC = (2 * PW + 2 * (PH - 2)) * C;
  int t = blockIdx.x * 256 + threadIdx.x;
  if (t >= nimg * RC) return;
  const int nl = t / RC;
  int rem = t - nl * RC;
  const int p = rem / C;
  const int ch = rem - p * C;
  int r, c;
  if (p < 2 * PW) {
    r = (p < PW) ? 0 : PH - 1;
    c = (p < PW) ? p : p - PW;
  } else {
    int q = p - 2 * PW;
    if (q < PH - 2) { r = 1 + q; c = 0; }
    else { r = 1 + q - (PH - 2); c = PW - 1; }
  }
  h[(((size_t)nl * PH + r) * PW + c) * C + ch] = 0;
}

// ---------------- conv1: fp32 direct, writes xt [nh][130][130][32] --------
__global__ __launch_bounds__(256) void conv1_xt(const float* __restrict__ x,
                                                const float* __restrict__ w,
                                                const float* __restrict__ bias,
                                                short* __restrict__ oh,
                                                short* __restrict__ ol, int NH) {
  int t = blockIdx.x * 256 + threadIdx.x;
  if (t >= NH * 128 * 128) return;
  const int px = t & 16383;
  const int n  = t >> 14;
  const int r = px >> 7, c = px & 127;
  const int ih0 = 2 * r - 1, iw0 = 2 * c - 1;
  float acc[32];
#pragma unroll
  for (int o = 0; o < 32; ++o) acc[o] = bias[o];
  const float* ip = x + (size_t)n * 2 * 65536;
#pragma unroll
  for (int ic = 0; ic < 2; ++ic, ip += 65536) {
    float v[9];
#pragma unroll
    for (int kh = 0; kh < 3; ++kh) {
      const int ih = ih0 + kh;
#pragma unroll
      for (int kw = 0; kw < 3; ++kw) {
        const int iw = iw0 + kw;
        const bool ok = (ih >= 0) && (ih < 256) && (iw >= 0) && (iw < 256);
        v[kh * 3 + kw] = ok ? ip[ih * 256 + iw] : 0.f;
      }
    }
#pragma unroll
    for (int o = 0; o < 32; ++o) {
      float s = acc[o];
#pragma unroll
      for (int k = 0; k < 9; ++k) s = fmaf(v[k], w[(o * 2 + ic) * 9 + k], s);
      acc[o] = s;
    }
  }
  const size_t base = (((size_t)n * 130 + r + 1) * 130 + (c + 1)) * 32;
  short8 vh[4], vl[4];
#pragma unroll
  for (int g = 0; g < 4; ++g) {
#pragma unroll
    for (int kk = 0; kk < 8; ++kk) {
      const float rv = fmaxf(acc[g * 8 + kk], 0.f);
      const unsigned short hh = bf16rn(rv);
      vh[g][kk] = (short)hh;
      vl[g][kk] = (short)bf16rn(rv - __uint_as_float((unsigned)hh << 16));
    }
    *(short8*)(oh + base + g * 8) = vh[g];
    *(short8*)(ol + base + g * 8) = vl[g];
  }
}

// ---------------- A-frag prep: conv weights [COUT][CIN][3][3], split ------
template<int CIN, int COUT>
__global__ __launch_bounds__(256) void wprep_conv(const float* __restrict__ w,
                                                  short* __restrict__ hi,
                                                  short* __restrict__ lo) {
  constexpr int MT = COUT / 16;
  const int t = blockIdx.x * 256 + threadIdx.x;
  const int j = t & 7;
  const int lane = (t >> 3) & 63;
  const int g = t >> 9;
  const int mt = g % MT;
  const int s = g / MT;
  const int icb = s / 9, tap = s - icb * 9;
  const int kh = tap / 3, kw = tap - kh * 3;
  const int m = mt * 16 + (lane & 15);
  const int ic = icb * 32 + ((lane >> 4) << 3) + j;
  const float v = w[((m * CIN + ic) * 3 + kh) * 3 + kw];
  const unsigned short h = bf16rn(v);
  hi[t] = (short)h;
  lo[t] = (short)bf16rn(v - __uint_as_float((unsigned)h << 16));
}

// ---------------- deconv A-frag prep: [CIN][COUT][3][3], hi-only ----------
template<int CIN, int COUT>
__global__ __launch_bounds__(256) void wprep_dec_h(const float* __restrict__ w,
                                                   short* __restrict__ hi) {
  constexpr int MT = COUT / 16, ICB = CIN / 32;
  const int t = blockIdx.x * 256 + threadIdx.x;
  const int j = t & 7;
  const int lane = (t >> 3) & 63;
  const int g = t >> 9;
  const int mt = g % MT;
  const int u = g / MT;
  const int icb = u % ICB;
  const int e = u / ICB;
  const int ky = DKY[e], kx = DKX[e];
  const int m = mt * 16 + (lane & 15);
  const int ic = icb * 32 + ((lane >> 4) << 3) + j;
  hi[t] = (short)bf16rn(w[((ic * COUT + m) * 3 + ky) * 3 + kx]);
}

// -- generic strided conv MFMA (split xt -> split xt), NP tiles, MGS groups -
template<int CIN, int COUT, int OH, int OW, int S, int PHI, int PWI, int PHO, int PWO, int NP, int MGS>
__global__ __launch_bounds__(256) void conv_mfma_xt(
    const short* __restrict__ xih, const short* __restrict__ xil,
    const short* __restrict__ ah,  const short* __restrict__ al,
    const float* __restrict__ bias,
    short* __restrict__ xoh, short* __restrict__ xol) {
  constexpr int MTF = COUT / 16, MTB = MTF / MGS, ICB = CIN / 32;
  constexpr int PXB = 64 * NP, TPB = OH * OW / PXB;
  const int b = blockIdx.x;
  const int mg = b % MGS;
  const int bb = b / MGS;
  const int n = bb / TPB, pt = bb % TPB;
  const int mt0 = mg * MTB;
  const int lane = threadIdx.x & 63, wave = threadIdx.x >> 6;
  const int quad = lane >> 4;
  int rr[NP], cc[NP];
  size_t bbase[NP];
#pragma unroll
  for (int p = 0; p < NP; ++p) {
    const int pl = pt * PXB + wave * (16 * NP) + p * 16 + (lane & 15);
    rr[p] = pl / OW; cc[p] = pl % OW;
    bbase[p] = (((size_t)n * PHI + S * rr[p]) * PWI + S * cc[p]) * CIN + quad * 8;
  }

  floatx4 acc[MTB][NP];
#pragma unroll
  for (int mt = 0; mt < MTB; ++mt)
#pragma unroll
    for (int p = 0; p < NP; ++p) acc[mt][p] = (floatx4){0.f, 0.f, 0.f, 0.f};

  const short8* __restrict__ ah8 = (const short8*)ah;
  const short8* __restrict__ al8 = (const short8*)al;

  for (int icb = 0; icb < ICB; ++icb) {
#pragma unroll
    for (int tap = 0; tap < 9; ++tap) {
      const int kh = tap / 3, kw = tap - kh * 3;
      short8 bh[NP], bl[NP];
#pragma unroll
      for (int p = 0; p < NP; ++p) {
        const size_t be = bbase[p] + (size_t)(kh * PWI + kw) * CIN + icb * 32;
        bh[p] = *(const short8*)(xih + be);
        bl[p] = *(const short8*)(xil + be);
      }
#pragma unroll
      for (int mt = 0; mt < MTB; ++mt) {
        const int fi = ((icb * 9 + tap) * MTF + (mt0 + mt)) * 64 + lane;
        const short8 wh = ah8[fi];
        const short8 wl = al8[fi];
#pragma unroll
        for (int p = 0; p < NP; ++p) {
          acc[mt][p] = __builtin_amdgcn_mfma_f32_16x16x32_bf16(wh, bh[p], acc[mt][p], 0, 0, 0);
          acc[mt][p] = __builtin_amdgcn_mfma_f32_16x16x32_bf16(wh, bl[p], acc[mt][p], 0, 0, 0);
          acc[mt][p] = __builtin_amdgcn_mfma_f32_16x16x32_bf16(wl, bh[p], acc[mt][p], 0, 0, 0);
        }
      }
    }
  }
#pragma unroll
  for (int p = 0; p < NP; ++p) {
    const size_t ob = (((size_t)n * PHO + rr[p] + 1) * PWO + (cc[p] + 1)) * COUT + quad * 4;
#pragma unroll
    for (int mt = 0; mt < MTB; ++mt) {
      short4v sh, sl;
#pragma unroll
      for (int q = 0; q < 4; ++q) {
        const float v = fmaxf(acc[mt][p][q] + bias[(mt0 + mt) * 16 + quad * 4 + q], 0.f);
        const unsigned short hh = bf16rn(v);
        sh[q] = (short)hh;
        sl[q] = (short)bf16rn(v - __uint_as_float((unsigned)hh << 16));
      }
      *(short4v*)(xoh + ob + (mt0 + mt) * 16) = sh;
      *(short4v*)(xol + ob + (mt0 + mt) * 16) = sl;
    }
  }
}

// -- fused transposed conv, plain bf16, NP pixel-tiles, MGS m-groups -------
template<int CIN, int COUT, int IH, int IW, int PHI, int PWI, int PHO, int PWO, int NP, int MGS>
__global__ __launch_bounds__(256) void deconv_bf16_xt(
    const short* __restrict__ xih, const short* __restrict__ ah,
    const float* __restrict__ bias, short* __restrict__ xoh) {
  constexpr int MTF = COUT / 16, MTB = MTF / MGS, ICB = CIN / 32;
  constexpr int PXB = 64 * NP, TPB = IH * IW / PXB;
  constexpr int PHE[9] = {0, 1, 1, 2, 2, 3, 3, 3, 3};
  constexpr int DE[9]  = {0, 0, 1, 0, 2, 0, 1, 2, 3};
  const int b = blockIdx.x;
  const int mg = b % MGS;
  const int bb = b / MGS;
  const int n = bb / TPB, pt = bb % TPB;
  const int mt0 = mg * MTB;
  const int lane = threadIdx.x & 63, wave = threadIdx.x >> 6;
  const int quad = lane >> 4;
  int ii[NP], jj[NP];
  size_t p00[NP];
#pragma unroll
  for (int p = 0; p < NP; ++p) {
    const int pl = pt * PXB + wave * (16 * NP) + p * 16 + (lane & 15);
    ii[p] = pl / IW; jj[p] = pl % IW;
    p00[p] = (((size_t)n * PHI + (ii[p] + 1)) * PWI + (jj[p] + 1)) * CIN + quad * 8;
  }

  floatx4 acc[4][MTB][NP];
#pragma unroll
  for (int ph = 0; ph < 4; ++ph)
#pragma unroll
    for (int mt = 0; mt < MTB; ++mt)
#pragma unroll
      for (int p = 0; p < NP; ++p) acc[ph][mt][p] = (floatx4){0.f, 0.f, 0.f, 0.f};

  const short8* __restrict__ ah8 = (const short8*)ah;
  for (int icb = 0; icb < ICB; ++icb) {
    short8 bh[NP][4];
#pragma unroll
    for (int p = 0; p < NP; ++p)
#pragma unroll
      for (int d = 0; d < 4; ++d)
        bh[p][d] = *(const short8*)(xih + p00[p] +
                                    (size_t)((d >> 1) * PWI + (d & 1)) * CIN + icb * 32);
#pragma unroll
    for (int e = 0; e < 9; ++e) {
      const int ph = PHE[e], d = DE[e];
#pragma unroll
      for (int mt = 0; mt < MTB; ++mt) {
        const short8 wh = ah8[((e * ICB + icb) * MTF + (mt0 + mt)) * 64 + lane];
#pragma unroll
        for (int p = 0; p < NP; ++p)
          acc[ph][mt][p] = __builtin_amdgcn_mfma_f32_16x16x32_bf16(
              wh, bh[p][d], acc[ph][mt][p], 0, 0, 0);
      }
    }
  }
#pragma unroll
  for (int p = 0; p < NP; ++p)
#pragma unroll
    for (int ph = 0; ph < 4; ++ph) {
      const int oy = 2 * ii[p] + (ph >> 1), ox = 2 * jj[p] + (ph & 1);
      const size_t ob = (((size_t)n * PHO + oy + 1) * PWO + (ox + 1)) * COUT + quad * 4;
#pragma unroll
      for (int mt = 0; mt < MTB; ++mt) {
        short4v sh;
#pragma unroll
        for (int q = 0; q < 4; ++q)
          sh[q] = (short)bf16rn(fmaxf(acc[ph][mt][p][q] + bias[(mt0 + mt) * 16 + quad * 4 + q], 0.f));
        *(short4v*)(xoh + ob + (mt0 + mt) * 16) = sh;
      }
    }
}

// ------- conv4 MFMA, NP=2, LDS A-frag staging (double-buffered) -----------
__global__ __launch_bounds__(256) void conv4_mfma(
    const short* __restrict__ xthi, const short* __restrict__ xtlo,
    const short* __restrict__ ahi,  const short* __restrict__ alo,
    const float* __restrict__ bias,
    short* __restrict__ ench, short* __restrict__ encl) {
  __shared__ short lah[2][8][64][8];   // 16 KB
  __shared__ short lal[2][8][64][8];   // 16 KB
  const int b    = blockIdx.x;         // N*8 blocks, 128 px each
  const int n    = b >> 3;
  const int pt   = b & 7;
  const int lane = threadIdx.x & 63;
  const int wave = threadIdx.x >> 6;
  const int kq   = lane >> 4;
  const int mta = wave, mtb = wave + 4;  // this wave's staging m-tiles
  int pl[2];
  size_t bbase[2];
#pragma unroll
  for (int p = 0; p < 2; ++p) {
    pl[p] = pt * 128 + wave * 32 + p * 16 + (lane & 15);
    const int r = pl[p] >> 5, c = pl[p] & 31;
    bbase[p] = (((size_t)n * 34 + r) * 34 + c) * 128 + kq * 8;
  }

  floatx4 acc[8][2];
#pragma unroll
  for (int mt = 0; mt < 8; ++mt)
#pragma unroll
    for (int p = 0; p < 2; ++p) acc[mt][p] = (floatx4){0.f, 0.f, 0.f, 0.f};

  const short8* __restrict__ ah8 = (const short8*)ahi;
  const short8* __restrict__ al8 = (const short8*)alo;

  // stage s=0 into buf 0
  *(short8*)&lah[0][mta][lane][0] = ah8[mta * 64 + lane];
  *(short8*)&lal[0][mta][lane][0] = al8[mta * 64 + lane];
  *(short8*)&lah[0][mtb][lane][0] = ah8[mtb * 64 + lane];
  *(short8*)&lal[0][mtb][lane][0] = al8[mtb * 64 + lane];
  __syncthreads();

  int s = 0;
  for (int icb = 0; icb < 4; ++icb) {
#pragma unroll
    for (int tap = 0; tap < 9; ++tap, ++s) {
      const int cur = s & 1, nxt = cur ^ 1;
      const int kh = tap / 3, kw = tap - kh * 3;
      // issue staging loads for s+1 (consumed after MFMAs)
      short8 th0, tl0, th1, tl1;
      const bool more = (s + 1) < 36;
      if (more) {
        const int f1 = (s + 1) * 8;
        th0 = ah8[(f1 + mta) * 64 + lane];
        tl0 = al8[(f1 + mta) * 64 + lane];
        th1 = ah8[(f1 + mtb) * 64 + lane];
        tl1 = al8[(f1 + mtb) * 64 + lane];
      }
      // B loads
      short8 bh[2], bl[2];
#pragma unroll
      for (int p = 0; p < 2; ++p) {
        const size_t be = bbase[p] + (size_t)(kh * 34 + kw) * 128 + icb * 32;
        bh[p] = *(const short8*)(xthi + be);
        bl[p] = *(const short8*)(xtlo + be);
      }
      // compute from LDS (cur)
#pragma unroll
      for (int mt = 0; mt < 8; ++mt) {
        const short8 ah = *(const short8*)&lah[cur][mt][lane][0];
        const short8 al = *(const short8*)&lal[cur][mt][lane][0];
#pragma unroll
        for (int p = 0; p < 2; ++p) {
          acc[mt][p] = __builtin_amdgcn_mfma_f32_16x16x32_bf16(ah, bh[p], acc[mt][p], 0, 0, 0);
          acc[mt][p] = __builtin_amdgcn_mfma_f32_16x16x32_bf16(ah, bl[p], acc[mt][p], 0, 0, 0);
          acc[mt][p] = __builtin_amdgcn_mfma_f32_16x16x32_bf16(al, bh[p], acc[mt][p], 0, 0, 0);
        }
      }
      // commit staged frags to LDS (nxt)
      if (more) {
        *(short8*)&lah[nxt][mta][lane][0] = th0;
        *(short8*)&lal[nxt][mta][lane][0] = tl0;
        *(short8*)&lah[nxt][mtb][lane][0] = th1;
        *(short8*)&lal[nxt][mtb][lane][0] = tl1;
      }
      __syncthreads();
    }
  }
#pragma unroll
  for (int p = 0; p < 2; ++p) {
    const size_t obase = (size_t)n * 128 * 1024 + pl[p];
#pragma unroll
    for (int mt = 0; mt < 8; ++mt) {
#pragma unroll
      for (int q = 0; q < 4; ++q) {
        const int cout = mt * 16 + kq * 4 + q;
        const float rr = fmaxf(acc[mt][p][q] + bias[cout], 0.f);
        const unsigned short h = bf16rn(rr);
        const size_t oi = obase + (size_t)cout * 1024;
        ench[oi] = (short)h;
        encl[oi] = (short)bf16rn(rr - __uint_as_float((unsigned)h << 16));
      }
    }
  }
}

// ------------------------------- VQ ---------------------------------------
__global__ __launch_bounds__(256) void vq_norms(const float* __restrict__ emb,
                                                float* __restrict__ norms) {
  int jj = blockIdx.x * 256 + threadIdx.x;
  if (jj < 512) {
    float s = 0.f;
    const float* e = emb + jj * 64;
#pragma unroll
    for (int k = 0; k < 64; ++k) s = fmaf(e[k], e[k], s);
    norms[jj] = s;
  }
}

__global__ __launch_bounds__(256) void emb_prep(const float* __restrict__ emb,
                                                short* __restrict__ hi,
                                                short* __restrict__ lo) {
  const int t = blockIdx.x * 256 + threadIdx.x;  // < 32768
  const int j  = t & 7;
  const int l  = (t >> 3) & 63;
  const int kk = (t >> 9) & 1;
  const int ct = t >> 10;
  const int code = ct * 16 + (l & 15);
  const int k = kk * 32 + ((l >> 4) << 3) + j;
  const float v = emb[code * 64 + k];
  const unsigned short h = bf16rn(v);
  hi[t] = (short)h;
  lo[t] = (short)bf16rn(v - __uint_as_float((unsigned)h << 16));
}

// scoring split-bf16 (proven); gather writes single-bf16 xt for decoder.
__global__ __launch_bounds__(256) void vq_mfma(
    const short* __restrict__ fhi, const short* __restrict__ flo,
    const short* __restrict__ ebh, const short* __restrict__ ebl,
    const float* __restrict__ nrm, const float* __restrict__ emb,
    short* __restrict__ d1h) {
  __shared__ int sidx[64];
  const int lane = threadIdx.x & 63;
  const int wave = threadIdx.x >> 6;
  const int r0 = blockIdx.x * 64 + wave * 16;
  const size_t abase = ((size_t)(r0 + (lane & 15))) * 64 + ((lane >> 4) << 3);
  short8 ah0 = *(const short8*)(fhi + abase);
  short8 ah1 = *(const short8*)(fhi + abase + 32);
  short8 al0 = *(const short8*)(flo + abase);
  short8 al1 = *(const short8*)(flo + abase + 32);

  float bestv[4] = {3.4e38f, 3.4e38f, 3.4e38f, 3.4e38f};
  int   besti[4] = {0, 0, 0, 0};
  const short8* __restrict__ ebh8 = (const short8*)ebh;
  const short8* __restrict__ ebl8 = (const short8*)ebl;
  for (int ct = 0; ct < 32; ++ct) {
    const int f0 = (ct * 2) * 64 + lane;
    const short8 b0h = ebh8[f0];
    const short8 b1h = ebh8[f0 + 64];
    const short8 b0l = ebl8[f0];
    const short8 b1l = ebl8[f0 + 64];
    floatx4 acc = {0.f, 0.f, 0.f, 0.f};
    acc = __builtin_amdgcn_mfma_f32_16x16x32_bf16(ah0, b0h, acc, 0, 0, 0);
    acc = __builtin_amdgcn_mfma_f32_16x16x32_bf16(ah1, b1h, acc, 0, 0, 0);
    acc = __builtin_amdgcn_mfma_f32_16x16x32_bf16(ah0, b0l, acc, 0, 0, 0);
    acc = __builtin_amdgcn_mfma_f32_16x16x32_bf16(ah1, b1l, acc, 0, 0, 0);
    acc = __builtin_amdgcn_mfma_f32_16x16x32_bf16(al0, b0h, acc, 0, 0, 0);
    acc = __builtin_amdgcn_mfma_f32_16x16x32_bf16(al1, b1h, acc, 0, 0, 0);
    const int code = ct * 16 + (lane & 15);
    const float nn = nrm[code];
#pragma unroll
    for (int q = 0; q < 4; ++q) {
      const float sc = nn - 2.f * acc[q];
      if (sc < bestv[q]) { bestv[q] = sc; besti[q] = code; }
    }
  }
#pragma unroll
  for (int off = 1; off < 16; off <<= 1) {
#pragma unroll
    for (int q = 0; q < 4; ++q) {
      const float ov = __shfl_xor(bestv[q], off, 64);
      const int   oi = __shfl_xor(besti[q], off, 64);
      if (ov < bestv[q] || (ov == bestv[q] && oi < besti[q])) {
        bestv[q] = ov; besti[q] = oi;
      }
    }
  }
  if ((lane & 15) == 0) {
#pragma unroll
    for (int q = 0; q < 4; ++q)
      sidx[wave * 16 + (lane >> 4) * 4 + q] = besti[q];
  }
  __syncthreads();
  const int row  = threadIdx.x >> 2;
  const int part = threadIdx.x & 3;
  const int rid = blockIdx.x * 64 + row;
  const int n  = rid >> 11;
  const int ch = (rid >> 4) & 127;
  const int pb = rid & 15;
  const int gi = sidx[row];
  const float4* src = (const float4*)(emb + (size_t)gi * 64 + part * 16);
  float4 v0 = src[0], v1 = src[1], v2 = src[2], v3 = src[3];
  float vals[16] = {v0.x, v0.y, v0.z, v0.w, v1.x, v1.y, v1.z, v1.w,
                    v2.x, v2.y, v2.z, v2.w, v3.x, v3.y, v3.z, v3.w};
#pragma unroll
  for (int kk = 0; kk < 16; ++kk) {
    const int k = part * 16 + kk;
    const int pix = pb * 64 + k;
    const int r = pix >> 5, c = pix & 31;
    const size_t a = (((size_t)n * 34 + r + 1) * 34 + (c + 1)) * 128 + ch;
    d1h[a] = (short)bf16rn(vals[kk]);
  }
}

// ---------------- dec3: fp32 direct from single-bf16 xt input -------------
__global__ __launch_bounds__(256) void dec3_xt(const short* __restrict__ xh,
                                               const float* __restrict__ w,
                                               const float* __restrict__ bias,
                                               float* __restrict__ out, int NH) {
  int t = blockIdx.x * 256 + threadIdx.x;
  if (t >= NH * 128 * 128) return;
  const int px = t & 16383;
  const int nl = t >> 14;
  const int i = px >> 7, j = px & 127;
  const float b0 = bias[0];
  float a00 = b0, a01 = b0, a10 = b0, a11 = b0;
  const size_t base00 = (((size_t)nl * 130 + i + 1) * 130 + (j + 1)) * 32;
#pragma unroll
  for (int icg = 0; icg < 4; ++icg) {
    const short8 h00 = *(const short8*)(xh + base00 + icg * 8);
    const short8 h01 = *(const short8*)(xh + base00 + 32 + icg * 8);
    const short8 h10 = *(const short8*)(xh + base00 + 130 * 32 + icg * 8);
    const short8 h11 = *(const short8*)(xh + base00 + 130 * 32 + 32 + icg * 8);
#pragma unroll
    for (int kk = 0; kk < 8; ++kk) {
      const int ic = icg * 8 + kk;
      const float x00 = bf2f1(h00[kk]);
      const float x01 = bf2f1(h01[kk]);
      const float x10 = bf2f1(h10[kk]);
      const float x11 = bf2f1(h11[kk]);
      const float* wp = w + ic * 9;
      a00 = fmaf(x00, wp[4], a00);
      a01 = fmaf(x00, wp[5], fmaf(x01, wp[3], a01));
      a10 = fmaf(x00, wp[7], fmaf(x10, wp[1], a10));
      a11 = fmaf(x00, wp[8], fmaf(x01, wp[6], fmaf(x10, wp[2], fmaf(x11, wp[0], a11))));
    }
  }
  float* op = out + ((size_t)nl * 256 + 2 * i) * 256 + 2 * j;
  op[0] = a00; op[1] = a01; op[256] = a10; op[257] = a11;
}

// ---------------------------------------------------------------------------
extern "C" void kernel_launch(void* const* d_in, const int* in_sizes, int n_in,
                              void* d_out, int out_size, void* d_ws, size_t ws_size,
                              hipStream_t stream) {
  const float* x   = (const float*)d_in[0];
  const float* w1  = (const float*)d_in[1];
  const float* b1  = (const float*)d_in[2];
  const float* w2  = (const float*)d_in[3];
  const float* b2  = (const float*)d_in[4];
  const float* w3  = (const float*)d_in[5];
  const float* b3  = (const float*)d_in[6];
  const float* w4  = (const float*)d_in[7];
  const float* b4  = (const float*)d_in[8];
  const float* emb = (const float*)d_in[9];
  const float* dw1 = (const float*)d_in[10];
  const float* db1 = (const float*)d_in[11];
  const float* dw2 = (const float*)d_in[12];
  const float* db2 = (const float*)d_in[13];
  const float* dw3 = (const float*)d_in[14];
  const float* db3 = (const float*)d_in[15];
  float* outp = (float*)d_out;

  const int N = in_sizes[0] / (2 * 256 * 256);  // 64
  if (N & 1) return;
  const int NH = N / 2;

  // ---- arena (units: floats; 1 float = 2 shorts); R7-proven footprint ----
  const size_t sx3 = (size_t)N * 66 * 66 * 64;
  const size_t sx2 = (size_t)NH * 130 * 130 * 32;
  const size_t sx4 = (size_t)N * 34 * 34 * 128;
  const size_t se  = (size_t)N * 128 * 1024;
  const size_t sd1 = sx4;
  const size_t smalls = 512 + 18432 + 73728 + 147456 + 73728 + 18432 + 32768;
  const size_t need = (sx3 + sx4 + se + sd1 + smalls) * sizeof(float);
  if (ws_size < need) return;

  float* ws = (float*)d_ws;
  short* x3h = (short*)ws;                 short* x3l = x3h + sx3;   // enc split
  short* x2h = (short*)(ws + sx3);         short* x2l = x2h + sx2;
  short* x4h = (short*)(ws + sx3);         short* x4l = x4h + sx4;
  short* ech = (short*)(ws + sx3 + sx4);   short* ecl = ech + se;
  short* d1h = (short*)(ws + sx3 + sx4 + se);   // bf16-only decoder bufs
  short* d2h = (short*)ws;
  short* d3h = (short*)(ws + sx3);
  float* sm  = ws + sx3 + sx4 + se + sd1;
  float* nrm = sm;
  short* a2h = (short*)(sm + 512);                         short* a2l = a2h + 18432;
  short* a3h = (short*)(sm + 512 + 18432);                 short* a3l = a3h + 73728;
  short* a4h = (short*)(sm + 512 + 18432 + 73728);         short* a4l = a4h + 147456;
  short* ad1h = (short*)(sm + 512 + 18432 + 73728 + 147456);           // hi only
  short* ad2h = (short*)(sm + 512 + 18432 + 73728 + 147456 + 73728);   // hi only
  short* ebh = (short*)(sm + 512 + 18432 + 73728 + 147456 + 73728 + 18432); short* ebl = ebh + 32768;

  // ---- weight preps + VQ tables ----
  wprep_conv<32, 64><<<72, 256, 0, stream>>>(w2, a2h, a2l);
  wprep_conv<64, 128><<<288, 256, 0, stream>>>(w3, a3h, a3l);
  wprep_conv<128, 128><<<576, 256, 0, stream>>>(w4, a4h, a4l);
  wprep_dec_h<128, 64><<<288, 256, 0, stream>>>(dw1, ad1h);
  wprep_dec_h<64, 32><<<72, 256, 0, stream>>>(dw2, ad2h);
  vq_norms<<<2, 256, 0, stream>>>(emb, nrm);
  emb_prep<<<128, 256, 0, stream>>>(emb, ebh, ebl);

  // ---- encoder (split-bf16, NP=2; conv3 MGS=2) ----
  ring_zero<<<(int)((NH * 516 * 32 + 255) / 256), 256, 0, stream>>>(x2h, x2l, NH, 130, 130, 32);
  ring_zero<<<(int)(((size_t)N * 260 * 64 + 255) / 256), 256, 0, stream>>>(x3h, x3l, N, 66, 66, 64);
  for (int half = 0; half < 2; ++half) {
    const int n0 = half * NH;
    conv1_xt<<<NH * 16384 / 256, 256, 0, stream>>>(
        x + (size_t)n0 * 2 * 65536, w1, b1, x2h, x2l, NH);
    conv_mfma_xt<32, 64, 64, 64, 2, 130, 130, 66, 66, 2, 1>
        <<<NH * 32, 256, 0, stream>>>(x2h, x2l, a2h, a2l, b2,
                                      x3h + (size_t)n0 * 66 * 66 * 64,
                                      x3l + (size_t)n0 * 66 * 66 * 64);
  }
  ring_zero<<<(int)(((size_t)N * 132 * 128 + 255) / 256), 256, 0, stream>>>(x4h, x4l, N, 34, 34, 128);
  conv_mfma_xt<64, 128, 32, 32, 2, 66, 66, 34, 34, 2, 2>
      <<<N * 16, 256, 0, stream>>>(x3h, x3l, a3h, a3l, b3, x4h, x4l);
  conv4_mfma<<<N * 8, 256, 0, stream>>>(x4h, x4l, a4h, a4l, b4, ech, ecl);

  // ---- VQ (split scoring, bf16 gather) ----
  ring_zero1<<<(int)(((size_t)N * 132 * 128 + 255) / 256), 256, 0, stream>>>(d1h, N, 34, 34, 128);
  vq_mfma<<<N * 2048 / 64, 256, 0, stream>>>(ech, ecl, ebh, ebl, nrm, emb, d1h);

  // ---- decoder (plain bf16, NP=2; deconv1 MGS=2) ----
  ring_zero1<<<(int)(((size_t)N * 260 * 64 + 255) / 256), 256, 0, stream>>>(d2h, N, 66, 66, 64);
  deconv_bf16_xt<128, 64, 32, 32, 34, 34, 66, 66, 2, 2>
      <<<N * 16, 256, 0, stream>>>(d1h, ad1h, db1, d2h);
  ring_zero1<<<(int)((NH * 516 * 32 + 255) / 256), 256, 0, stream>>>(d3h, NH, 130, 130, 32);
  for (int half = 0; half < 2; ++half) {
    const int n0 = half * NH;
    deconv_bf16_xt<64, 32, 64, 64, 66, 66, 130, 130, 2, 1>
        <<<NH * 32, 256, 0, stream>>>(d2h + (size_t)n0 * 66 * 66 * 64,
                                      ad2h, db2, d3h);
    dec3_xt<<<NH * 16384 / 256, 256, 0, stream>>>(
        d3h, dw3, db3, outp + (size_t)n0 * 65536, NH);
  }
}